// Round 11
// baseline (269.379 us; speedup 1.0000x reference)
//
#include <hip/hip_runtime.h>
#include <hip/hip_bf16.h>
#include <math.h>

#define BB 64
#define PP 100
#define NN 1000
#define DD 128
#define HH 8
#define QDQ 16
#define NTOT 1196
#define HALFK 598
#define CH 128
#define QROWS 16
#define LOG2E 1.44269504088896f
#define EXP2(x) __builtin_amdgcn_exp2f(x)

typedef float f2 __attribute__((ext_vector_type(2)));
static __device__ __forceinline__ f2 splat2(float v) { f2 r; r.x = v; r.y = v; return r; }
#define PKFMA(a, b, c) __builtin_elementwise_fma((a), (b), (c))

// ------- Kernel P: fused {q = q_first + x @ Wq^T} and {mask -> bf16 table} ----
// blocks 0..399: qcalc (16 bp-rows each); blocks 400..2831: mask tiles.
__global__ __launch_bounds__(256) void k_prep(const float* __restrict__ x,
                                              const float* __restrict__ Wq,
                                              const float* __restrict__ qf,
                                              float* __restrict__ qout,
                                              const float* __restrict__ mask,
                                              __hip_bfloat16* __restrict__ mt) {
  __shared__ float sw[128 * 65];       // qcalc: W[j][dl] padded; mask: tile alias
  __shared__ float xs[QROWS * DD];
  int tid = threadIdx.x;

  if (blockIdx.x < 400) {
    int row0 = blockIdx.x * QROWS;
    for (int i = tid; i < QROWS * DD / 4; i += 256)
      ((float4*)xs)[i] = ((const float4*)(x + (size_t)row0 * DD))[i];

    int j = tid & 127, rr = tid >> 7;
    float acc[8];
#pragma unroll
    for (int i = 0; i < 8; ++i) acc[i] = 0.f;

    for (int half = 0; half < 2; ++half) {
      __syncthreads();
      for (int idx = tid; idx < 128 * 64; idx += 256) {
        int jj = idx >> 6, dl = idx & 63;
        sw[jj * 65 + dl] = Wq[jj * DD + half * 64 + dl];   // coalesced row reads
      }
      __syncthreads();
#pragma unroll
      for (int ri = 0; ri < 8; ++ri) {
        int r = 2 * ri + rr;
        float a = acc[ri];
#pragma unroll 16
        for (int dl = 0; dl < 64; ++dl)
          a += xs[r * DD + half * 64 + dl] * sw[j * 65 + dl];
        acc[ri] = a;
      }
    }
#pragma unroll
    for (int ri = 0; ri < 8; ++ri) {
      int bp = row0 + 2 * ri + rr;
      int b = bp / PP, p = bp % PP;
      int h = j >> 4, qd = j & 15;
      size_t qi = ((size_t)(b * HH + h) * PP + p) * QDQ + qd;
      qout[qi] = acc[ri] + qf[qi];
    }
  } else {
    // mask transpose+pad -> bf16 mt[b][n][p'] = mask*log2e - 20
    // p' pair-packs (p, p+64) into one dword: p' = 2*(p&63) | (p>>6)
    float (*tile)[65] = (float(*)[65])sw;
    int t = blockIdx.x - 400;
    int b = t / 38, rem = t % 38;
    int nt = rem % 19, pt = rem / 19;
    int tx = tid & 63, ty = tid >> 6;
    int n0 = nt * 64, p0 = pt * 64;
#pragma unroll
    for (int r = ty; r < 64; r += 4) {
      int p = p0 + r, n = n0 + tx;
      tile[r][tx] = (p < PP && n < NN) ? mask[((size_t)b * PP + p) * NN + n] * LOG2E - 20.f
                                       : -20.f;
    }
    __syncthreads();
#pragma unroll
    for (int r = ty; r < 64; r += 4) {
      int n = n0 + r, p = p0 + tx;
      int pp = ((p & 63) << 1) | (p >> 6);
      if (n < NTOT)
        mt[((size_t)b * NTOT + n) * 128 + pp] = __float2bfloat16(tile[tx][r]);
    }
  }
}

// ---------------- Kernel B: MHA partial — 2q/lane packed f32, bf16 mask -------
// grid = 1024 (XCD-swizzled: 512 bh * 2 halves); block = 512 (8 waves)
// wave w handles keys {w, w+8, ...}; lane owns queries (lane, lane+64) packed
// into float2 -> v_pk_fma_f32. Fixed -20 offset in mt -> w = exp2(s), sums only.
__global__ __launch_bounds__(512) void k_mha(const float* __restrict__ kk,
                                             const float* __restrict__ vv,
                                             const float* __restrict__ qws,
                                             const unsigned int* __restrict__ mt32,
                                             float* __restrict__ part) {
  int bid = blockIdx.x;
  int swz = (bid & 7) * 128 + (bid >> 3);      // 16 blocks of same b per XCD
  int bh = swz >> 1, half = swz & 1;
  int b = bh >> 3;
  int tid = threadIdx.x;
  int w = tid >> 6;           // wave 0..7
  int lane = tid & 63;
  int p2 = lane + 64;
  int pc2 = p2 < PP ? p2 : PP - 1;

  __shared__ __align__(16) float smem_f[8192]; // 32 KB: k/v dbuf, then merge area
  float4* s4 = (float4*)smem_f;                // [buf][k 512 f4 | v 512 f4]

  f2 qp[QDQ];                                  // (q1, q2) pairs
  const float sc0 = 0.25f * LOG2E;
  {
    const float* qrow1 = qws + ((size_t)bh * PP + lane) * QDQ;
    const float* qrow2 = qws + ((size_t)bh * PP + pc2) * QDQ;
#pragma unroll
    for (int jj = 0; jj < QDQ; ++jj) {
      qp[jj].x = qrow1[jj] * sc0;
      qp[jj].y = qrow2[jj] * sc0;
    }
  }

  f2 accp[QDQ];
#pragma unroll
  for (int jj = 0; jj < QDQ; ++jj) accp[jj] = splat2(0.f);
  f2 lp = splat2(0.f);

  const float4* kg4 = (const float4*)(kk + (size_t)bh * NTOT * QDQ);
  const float4* vg4 = (const float4*)(vv + (size_t)bh * NTOT * QDQ);
  int key0 = half * HALFK;
  int gbase = key0 * 4;
  int lim = NTOT * 4 - 1;

  float4 rk, rv;
  { int gi = gbase + tid; gi = gi < lim ? gi : lim; rk = kg4[gi]; rv = vg4[gi]; }

  int cur = 0;
  for (int c = 0; c < 5; ++c) {                // 598 = 4*128 + 86
    int base = c * CH;
    int L = HALFK - base; if (L > CH) L = CH;
    __syncthreads();
    s4[cur * 1024 + tid] = rk;
    s4[cur * 1024 + 512 + tid] = rv;
    __syncthreads();
    if (c < 4) {
      int gi = gbase + (c + 1) * 512 + tid; gi = gi < lim ? gi : lim;
      rk = kg4[gi]; rv = vg4[gi];
    }
    const unsigned int* mrow = mt32 + ((size_t)b * NTOT + key0 + base) * 64;
    int kb = cur * 1024, vb = cur * 1024 + 512;

    unsigned int nmm = mrow[w * 64 + lane];    // pipelined mask (1 key ahead)
    for (int i = w; i < L; i += 8) {
      unsigned int mm = nmm;
      int inx = i + 8; inx = inx < L ? inx : i;
      nmm = mrow[inx * 64 + lane];

      f2 sp;                                    // dot starts from mask pair
      sp.x = __uint_as_float(mm << 16);
      sp.y = __uint_as_float(mm & 0xffff0000u);
      float4 k0 = s4[kb + i * 4 + 0], k1 = s4[kb + i * 4 + 1];
      float4 k2 = s4[kb + i * 4 + 2], k3 = s4[kb + i * 4 + 3];
      sp = PKFMA(qp[0],  splat2(k0.x), sp);
      sp = PKFMA(qp[1],  splat2(k0.y), sp);
      sp = PKFMA(qp[2],  splat2(k0.z), sp);
      sp = PKFMA(qp[3],  splat2(k0.w), sp);
      sp = PKFMA(qp[4],  splat2(k1.x), sp);
      sp = PKFMA(qp[5],  splat2(k1.y), sp);
      sp = PKFMA(qp[6],  splat2(k1.z), sp);
      sp = PKFMA(qp[7],  splat2(k1.w), sp);
      sp = PKFMA(qp[8],  splat2(k2.x), sp);
      sp = PKFMA(qp[9],  splat2(k2.y), sp);
      sp = PKFMA(qp[10], splat2(k2.z), sp);
      sp = PKFMA(qp[11], splat2(k2.w), sp);
      sp = PKFMA(qp[12], splat2(k3.x), sp);
      sp = PKFMA(qp[13], splat2(k3.y), sp);
      sp = PKFMA(qp[14], splat2(k3.z), sp);
      sp = PKFMA(qp[15], splat2(k3.w), sp);

      f2 wp;
      wp.x = EXP2(sp.x);
      wp.y = EXP2(sp.y);
      lp += wp;

      float4 v0 = s4[vb + i * 4 + 0], v1 = s4[vb + i * 4 + 1];
      float4 v2 = s4[vb + i * 4 + 2], v3 = s4[vb + i * 4 + 3];
      accp[0]  = PKFMA(wp, splat2(v0.x), accp[0]);
      accp[1]  = PKFMA(wp, splat2(v0.y), accp[1]);
      accp[2]  = PKFMA(wp, splat2(v0.z), accp[2]);
      accp[3]  = PKFMA(wp, splat2(v0.w), accp[3]);
      accp[4]  = PKFMA(wp, splat2(v1.x), accp[4]);
      accp[5]  = PKFMA(wp, splat2(v1.y), accp[5]);
      accp[6]  = PKFMA(wp, splat2(v1.z), accp[6]);
      accp[7]  = PKFMA(wp, splat2(v1.w), accp[7]);
      accp[8]  = PKFMA(wp, splat2(v2.x), accp[8]);
      accp[9]  = PKFMA(wp, splat2(v2.y), accp[9]);
      accp[10] = PKFMA(wp, splat2(v2.z), accp[10]);
      accp[11] = PKFMA(wp, splat2(v2.w), accp[11]);
      accp[12] = PKFMA(wp, splat2(v3.x), accp[12]);
      accp[13] = PKFMA(wp, splat2(v3.y), accp[13]);
      accp[14] = PKFMA(wp, splat2(v3.z), accp[14]);
      accp[15] = PKFMA(wp, splat2(v3.w), accp[15]);
    }
    cur ^= 1;
  }

  // ---- 8->1 merge (pure sums), 2-phase over 4-record LDS area [4][PP][17] ----
  __syncthreads();
  if (w < 4) {
    float* r = smem_f + ((size_t)w * PP + lane) * 17;
#pragma unroll
    for (int jj = 0; jj < QDQ; ++jj) r[jj] = accp[jj].x;
    r[16] = lp.x;
    if (p2 < PP) {
      float* r2 = smem_f + ((size_t)w * PP + p2) * 17;
#pragma unroll
      for (int jj = 0; jj < QDQ; ++jj) r2[jj] = accp[jj].y;
      r2[16] = lp.y;
    }
  }
  __syncthreads();
  if (w >= 4) {
    float* r = smem_f + ((size_t)(w - 4) * PP + lane) * 17;
#pragma unroll
    for (int jj = 0; jj < QDQ; ++jj) r[jj] += accp[jj].x;
    r[16] += lp.x;
    if (p2 < PP) {
      float* r2 = smem_f + ((size_t)(w - 4) * PP + p2) * 17;
#pragma unroll
      for (int jj = 0; jj < QDQ; ++jj) r2[jj] += accp[jj].y;
      r2[16] += lp.y;
    }
  }
  __syncthreads();
  for (int idx = tid; idx < PP * 17; idx += 512) {
    int pp2 = idx / 17, e = idx % 17;
    float vsum = smem_f[(0 * PP + pp2) * 17 + e] + smem_f[(1 * PP + pp2) * 17 + e]
               + smem_f[(2 * PP + pp2) * 17 + e] + smem_f[(3 * PP + pp2) * 17 + e];
    part[((size_t)swz * PP + pp2) * 17 + e] = vsum;
  }
}

// ---------------- Kernel C: merge 2 halves (sum) + mh_combine (LDS GEMM) ------
__global__ __launch_bounds__(256) void k_combine(const float* __restrict__ part,
                                                 const float* __restrict__ MC,
                                                 float* __restrict__ mh) {
  __shared__ float sw[128 * 65];       // MC[j][dl] current half, padded
  __shared__ float oc[QROWS * DD];
  int tid = threadIdx.x;
  int row0 = blockIdx.x * QROWS;

  for (int i = tid; i < QROWS * DD; i += 256) {
    int r = i >> 7, t = i & 127;
    int bp = row0 + r, b = bp / PP, p = bp % PP;
    int qd = t & 15, h = t >> 4;
    int bh = b * HH + h;
    const float* r0 = part + (((size_t)(bh * 2 + 0)) * PP + p) * 17;
    const float* r1 = part + (((size_t)(bh * 2 + 1)) * PP + p) * 17;
    float A = r0[qd] + r1[qd];
    float L = r0[16] + r1[16];
    oc[i] = A / L;
  }

  int j = tid & 127, rr = tid >> 7;
  float acc[8];
#pragma unroll
  for (int i = 0; i < 8; ++i) acc[i] = 0.f;

  for (int half = 0; half < 2; ++half) {
    __syncthreads();
    for (int idx = tid; idx < 128 * 64; idx += 256) {
      int jj = idx >> 6, dl = idx & 63;
      sw[jj * 65 + dl] = MC[jj * DD + half * 64 + dl];
    }
    __syncthreads();
#pragma unroll
    for (int ri = 0; ri < 8; ++ri) {
      int r = 2 * ri + rr;
      float a = acc[ri];
#pragma unroll 16
      for (int dl = 0; dl < 64; ++dl)
        a += oc[r * DD + half * 64 + dl] * sw[j * 65 + dl];
      acc[ri] = a;
    }
  }
#pragma unroll
  for (int ri = 0; ri < 8; ++ri) {
    int bp = row0 + 2 * ri + rr;
    mh[(size_t)bp * DD + j] = acc[ri];
  }
}

// ------- Kernel D: score2 (packed f32: two n-columns per accumulator) --------
__global__ __launch_bounds__(256) void k_score2(const float* __restrict__ mh,
                                                const float* __restrict__ shk,
                                                float* __restrict__ sc) {
  int bid = blockIdx.x;
  int swz = (bid & 7) * 128 + (bid >> 3);      // same-b blocks share an XCD
  int b = swz >> 4, nt = swz & 15;
  int tid = threadIdx.x; int nl = tid & 31, pg = tid >> 5;
  __shared__ float A[PP * 132];
  for (int idx = tid; idx < PP * DD; idx += 256)
    A[(idx >> 7) * 132 + (idx & 127)] = mh[(size_t)b * PP * DD + idx];
  __syncthreads();

  int na = nt * 64 + nl, nb2 = na + 32;
  int nca = na < NN ? na : NN - 1, ncb = nb2 < NN ? nb2 : NN - 1;
  const float* S = shk + (size_t)b * DD * NN;
  f2 accv[13];
#pragma unroll
  for (int i = 0; i < 13; ++i) accv[i] = splat2(0.f);

  for (int d = 0; d < DD; d += 4) {
    f2 s0, s1, s2, s3;
    s0.x = S[(size_t)(d + 0) * NN + nca]; s0.y = S[(size_t)(d + 0) * NN + ncb];
    s1.x = S[(size_t)(d + 1) * NN + nca]; s1.y = S[(size_t)(d + 1) * NN + ncb];
    s2.x = S[(size_t)(d + 2) * NN + nca]; s2.y = S[(size_t)(d + 2) * NN + ncb];
    s3.x = S[(size_t)(d + 3) * NN + nca]; s3.y = S[(size_t)(d + 3) * NN + ncb];
#pragma unroll
    for (int i = 0; i < 13; ++i) {
      int p = pg + (i << 3);
      if (p < PP) {
        const float4 a4 = *(const float4*)&A[p * 132 + d];
        accv[i] = PKFMA(splat2(a4.x), s0, accv[i]);
        accv[i] = PKFMA(splat2(a4.y), s1, accv[i]);
        accv[i] = PKFMA(splat2(a4.z), s2, accv[i]);
        accv[i] = PKFMA(splat2(a4.w), s3, accv[i]);
      }
    }
  }
#pragma unroll
  for (int i = 0; i < 13; ++i) {
    int p = pg + (i << 3);
    if (p < PP) {
      size_t base = ((size_t)b * PP + p) * NN;
      if (na < NN) sc[base + na] = accv[i].x;
      if (nb2 < NN) sc[base + nb2] = accv[i].y;
    }
  }
}

// ------- Kernel E: tanh clip + edge bias + mask + row softmax (no max pass) ---
// Logits bounded (|10 tanh| <= 10, bias small), so exp2 without max-subtraction
// is safe; masked -inf still -> 0 and no (-inf)-(-inf) NaN can occur.
__global__ __launch_bounds__(256) void k_finsm(const float* __restrict__ sc,
                                               const float* __restrict__ eb,
                                               const int* __restrict__ cn,
                                               const float* __restrict__ mask,
                                               float* __restrict__ out) {
  int bid = blockIdx.x;
  int bp = (bid & 7) * 800 + (bid >> 3);       // XCD swizzle (6400 % 8 == 0)
  int b = bp / PP;
  int t = threadIdx.x;
  int node = cn[bp];
  const float* scp = sc + (size_t)bp * NN;
  const float* ebp = eb + ((size_t)b * NN + node) * NN;
  const float* mp = mask + (size_t)bp * NN;
  const float inv_sqrtD = 0.08838834764831845f;  // 1/sqrt(128)

  float vals[4];
  float s = 0.f;
#pragma unroll
  for (int i = 0; i < 4; ++i) {
    int n = t + (i << 8);
    if (n < NN) {
      float z = scp[n] * inv_sqrtD;
      float e = EXP2(2.f * LOG2E * z);
      float th10 = 10.f - 20.f * __builtin_amdgcn_rcpf(e + 1.f);  // 10*tanh(z)
      float lg = th10 + ebp[n] + mp[n];
      float e2 = EXP2(lg * LOG2E);
      vals[i] = e2;
      s += e2;
    } else {
      vals[i] = 0.f;
    }
  }
#pragma unroll
  for (int off = 32; off; off >>= 1) s += __shfl_xor(s, off);
  __shared__ float red[4];
  int w = t >> 6, lane = t & 63;
  if (lane == 0) red[w] = s;
  __syncthreads();
  s = (red[0] + red[1]) + (red[2] + red[3]);
  float inv = 1.f / s;
#pragma unroll
  for (int i = 0; i < 4; ++i) {
    int n = t + (i << 8);
    if (n < NN) out[(size_t)bp * NN + n] = vals[i] * inv;
  }
}

extern "C" void kernel_launch(void* const* d_in, const int* in_sizes, int n_in,
                              void* d_out, int out_size, void* d_ws, size_t ws_size,
                              hipStream_t stream) {
  const float* x    = (const float*)d_in[0];   // encoded_last_node (B,P,D)
  const float* mask = (const float*)d_in[1];   // ninf_mask (B,P,N)
  const float* qf   = (const float*)d_in[2];   // q_first (B,H,P,QD)
  const float* kk   = (const float*)d_in[3];   // k (B,H,NTOT,QD)
  const float* vv   = (const float*)d_in[4];   // v (B,H,NTOT,QD)
  const float* shk  = (const float*)d_in[5];   // single_head_key (B,D,N)
  const float* Wq   = (const float*)d_in[6];   // (128,128)
  const float* MC   = (const float*)d_in[7];   // (128,128)
  const float* eb   = (const float*)d_in[8];   // edge_bias (B,N,N)
  const int*   cn   = (const int*)d_in[9];     // current_node (B,P)

  float* out = (float*)d_out;
  float* ws = (float*)d_ws;
  float* q_ws = ws;                            //   819,200 f
  float* part = ws + 819200;                   // 1,740,800 f (1024*100*17)
  float* mh   = ws + 2560000;                  //   819,200 f
  float* reg  = ws + 3379200;                  // 6,400,000 f shared region:
  __hip_bfloat16* mt = (__hip_bfloat16*)reg;   //   mt bf16 (9,797,632 ush = 4.9M f)
  float* sc   = reg;                           //   sc overlays mt (after last mt read)

  hipLaunchKernelGGL(k_prep, dim3(2832), dim3(256), 0, stream, x, Wq, qf, q_ws, mask, mt);
  hipLaunchKernelGGL(k_mha, dim3(1024), dim3(512), 0, stream, kk, vv, q_ws,
                     (const unsigned int*)mt, part);
  hipLaunchKernelGGL(k_combine, dim3(400), dim3(256), 0, stream, part, MC, mh);
  hipLaunchKernelGGL(k_score2, dim3(1024), dim3(256), 0, stream, mh, shk, sc);
  hipLaunchKernelGGL(k_finsm, dim3(6400), dim3(256), 0, stream, sc, eb, cn, mask, out);
}

// Round 12
// 219.921 us; speedup vs baseline: 1.2249x; 1.2249x over previous
//
#include <hip/hip_runtime.h>
#include <hip/hip_bf16.h>
#include <math.h>

#define BB 64
#define PP 100
#define NN 1000
#define DD 128
#define HH 8
#define QDQ 16
#define NTOT 1196
#define HALFK 598
#define CH 128
#define QROWS 16
#define LOG2E 1.44269504088896f
#define EXP2(x) __builtin_amdgcn_exp2f(x)

typedef float f2 __attribute__((ext_vector_type(2)));
static __device__ __forceinline__ f2 splat2(float v) { f2 r; r.x = v; r.y = v; return r; }
#define PKFMA(a, b, c) __builtin_elementwise_fma((a), (b), (c))

// ------- Kernel P: fused {q = q_first + x @ Wq^T} and {mask -> bf16 table} ----
// blocks 0..399: qcalc (16 bp-rows each); blocks 400..2831: mask tiles.
__global__ __launch_bounds__(256) void k_prep(const float* __restrict__ x,
                                              const float* __restrict__ Wq,
                                              const float* __restrict__ qf,
                                              float* __restrict__ qout,
                                              const float* __restrict__ mask,
                                              __hip_bfloat16* __restrict__ mt) {
  __shared__ float sw[128 * 65];       // qcalc: W[j][dl] padded; mask: tile alias
  __shared__ float xs[QROWS * DD];
  int tid = threadIdx.x;

  if (blockIdx.x < 400) {
    int row0 = blockIdx.x * QROWS;
    for (int i = tid; i < QROWS * DD / 4; i += 256)
      ((float4*)xs)[i] = ((const float4*)(x + (size_t)row0 * DD))[i];

    int j = tid & 127, rr = tid >> 7;
    float acc[8];
#pragma unroll
    for (int i = 0; i < 8; ++i) acc[i] = 0.f;

    for (int half = 0; half < 2; ++half) {
      __syncthreads();
      for (int idx = tid; idx < 128 * 64; idx += 256) {
        int jj = idx >> 6, dl = idx & 63;
        sw[jj * 65 + dl] = Wq[jj * DD + half * 64 + dl];   // coalesced row reads
      }
      __syncthreads();
#pragma unroll
      for (int ri = 0; ri < 8; ++ri) {
        int r = 2 * ri + rr;
        float a = acc[ri];
#pragma unroll 16
        for (int dl = 0; dl < 64; ++dl)
          a += xs[r * DD + half * 64 + dl] * sw[j * 65 + dl];
        acc[ri] = a;
      }
    }
#pragma unroll
    for (int ri = 0; ri < 8; ++ri) {
      int bp = row0 + 2 * ri + rr;
      int b = bp / PP, p = bp % PP;
      int h = j >> 4, qd = j & 15;
      size_t qi = ((size_t)(b * HH + h) * PP + p) * QDQ + qd;
      qout[qi] = acc[ri] + qf[qi];
    }
  } else {
    // mask transpose+pad -> bf16 mt[b][n][p'] = mask*log2e - 20
    // p' pair-packs (p, p+64) into one dword: p' = 2*(p&63) | (p>>6)
    float (*tile)[65] = (float(*)[65])sw;
    int t = blockIdx.x - 400;
    int b = t / 38, rem = t % 38;
    int nt = rem % 19, pt = rem / 19;
    int tx = tid & 63, ty = tid >> 6;
    int n0 = nt * 64, p0 = pt * 64;
#pragma unroll
    for (int r = ty; r < 64; r += 4) {
      int p = p0 + r, n = n0 + tx;
      tile[r][tx] = (p < PP && n < NN) ? mask[((size_t)b * PP + p) * NN + n] * LOG2E - 20.f
                                       : -20.f;
    }
    __syncthreads();
#pragma unroll
    for (int r = ty; r < 64; r += 4) {
      int n = n0 + r, p = p0 + tx;
      int pp = ((p & 63) << 1) | (p >> 6);
      if (n < NTOT)
        mt[((size_t)b * NTOT + n) * 128 + pp] = __float2bfloat16(tile[tx][r]);
    }
  }
}

// ---------------- Kernel B: MHA partial — 2q/lane, bf16 mask, raw v_exp -------
// grid = 1024 (XCD-swizzled: 512 bh * 2 halves); block = 512 (8 waves)
// wave w handles keys {w, w+8, ...} of each 128-key chunk; lane owns queries
// (lane, lane+64). Fixed -20 offset baked into mt -> w = exp2(s), sums only.
#define QKDOT(qv, K0, K1, K2, K3) \
  (qv[0] * K0.x + qv[1] * K0.y + qv[2] * K0.z + qv[3] * K0.w \
 + qv[4] * K1.x + qv[5] * K1.y + qv[6] * K1.z + qv[7] * K1.w \
 + qv[8] * K2.x + qv[9] * K2.y + qv[10] * K2.z + qv[11] * K2.w \
 + qv[12] * K3.x + qv[13] * K3.y + qv[14] * K3.z + qv[15] * K3.w)

#define PVADD(av, wt, V0, V1, V2, V3) { \
  av[0] += (wt) * V0.x;  av[1] += (wt) * V0.y;  av[2] += (wt) * V0.z;  av[3] += (wt) * V0.w; \
  av[4] += (wt) * V1.x;  av[5] += (wt) * V1.y;  av[6] += (wt) * V1.z;  av[7] += (wt) * V1.w; \
  av[8] += (wt) * V2.x;  av[9] += (wt) * V2.y;  av[10] += (wt) * V2.z; av[11] += (wt) * V2.w; \
  av[12] += (wt) * V3.x; av[13] += (wt) * V3.y; av[14] += (wt) * V3.z; av[15] += (wt) * V3.w; }

__global__ __launch_bounds__(512) void k_mha(const float* __restrict__ kk,
                                             const float* __restrict__ vv,
                                             const float* __restrict__ qws,
                                             const unsigned int* __restrict__ mt32,
                                             float* __restrict__ part) {
  int bid = blockIdx.x;
  int swz = (bid & 7) * 128 + (bid >> 3);      // 16 blocks of same b per XCD
  int bh = swz >> 1, half = swz & 1;
  int b = bh >> 3;
  int tid = threadIdx.x;
  int w = tid >> 6;           // wave 0..7
  int lane = tid & 63;
  int p2 = lane + 64;
  int pc2 = p2 < PP ? p2 : PP - 1;

  __shared__ __align__(16) float smem_f[8192]; // 32 KB: k/v dbuf, then merge area
  float4* s4 = (float4*)smem_f;                // [buf][k 512 f4 | v 512 f4]

  float q1[QDQ], q2[QDQ];
  const float sc0 = 0.25f * LOG2E;
  {
    const float* qrow1 = qws + ((size_t)bh * PP + lane) * QDQ;
    const float* qrow2 = qws + ((size_t)bh * PP + pc2) * QDQ;
#pragma unroll
    for (int jj = 0; jj < QDQ; jj += 4) {
      float4 a4 = *(const float4*)(qrow1 + jj);
      q1[jj] = a4.x * sc0; q1[jj + 1] = a4.y * sc0;
      q1[jj + 2] = a4.z * sc0; q1[jj + 3] = a4.w * sc0;
      float4 b4 = *(const float4*)(qrow2 + jj);
      q2[jj] = b4.x * sc0; q2[jj + 1] = b4.y * sc0;
      q2[jj + 2] = b4.z * sc0; q2[jj + 3] = b4.w * sc0;
    }
  }

  float acc1[QDQ], acc2[QDQ];
#pragma unroll
  for (int jj = 0; jj < QDQ; ++jj) { acc1[jj] = 0.f; acc2[jj] = 0.f; }
  float l1 = 0.f, l2 = 0.f;

  const float4* kg4 = (const float4*)(kk + (size_t)bh * NTOT * QDQ);
  const float4* vg4 = (const float4*)(vv + (size_t)bh * NTOT * QDQ);
  int key0 = half * HALFK;
  int gbase = key0 * 4;
  int lim = NTOT * 4 - 1;

  float4 rk, rv;
  { int gi = gbase + tid; gi = gi < lim ? gi : lim; rk = kg4[gi]; rv = vg4[gi]; }

  int cur = 0;
  for (int c = 0; c < 5; ++c) {                // 598 = 4*128 + 86
    int base = c * CH;
    int L = HALFK - base; if (L > CH) L = CH;
    __syncthreads();
    s4[cur * 1024 + tid] = rk;
    s4[cur * 1024 + 512 + tid] = rv;
    __syncthreads();
    if (c < 4) {
      int gi = gbase + (c + 1) * 512 + tid; gi = gi < lim ? gi : lim;
      rk = kg4[gi]; rv = vg4[gi];
    }
    const unsigned int* mrow = mt32 + ((size_t)b * NTOT + key0 + base) * 64;
    int kb = cur * 1024, vb = cur * 1024 + 512;

    unsigned int nmm = mrow[w * 64 + lane];    // pipelined mask (1 key ahead)
    for (int i = w; i < L; i += 8) {
      unsigned int mm = nmm;
      int inx = i + 8; inx = inx < L ? inx : i;
      nmm = mrow[inx * 64 + lane];

      float4 k0 = s4[kb + i * 4 + 0], k1 = s4[kb + i * 4 + 1];
      float4 k2 = s4[kb + i * 4 + 2], k3 = s4[kb + i * 4 + 3];
      float s1 = QKDOT(q1, k0, k1, k2, k3);
      float s2 = QKDOT(q2, k0, k1, k2, k3);
      float w1 = EXP2(s1 + __uint_as_float(mm << 16));
      float w2 = EXP2(s2 + __uint_as_float(mm & 0xffff0000u));
      l1 += w1; l2 += w2;
      float4 v0 = s4[vb + i * 4 + 0], v1 = s4[vb + i * 4 + 1];
      float4 v2 = s4[vb + i * 4 + 2], v3 = s4[vb + i * 4 + 3];
      PVADD(acc1, w1, v0, v1, v2, v3)
      PVADD(acc2, w2, v0, v1, v2, v3)
    }
    cur ^= 1;
  }

  // ---- 8->1 merge (pure sums), 2-phase over 4-record LDS area [4][PP][17] ----
  __syncthreads();
  if (w < 4) {
    float* r = smem_f + ((size_t)w * PP + lane) * 17;
#pragma unroll
    for (int jj = 0; jj < QDQ; ++jj) r[jj] = acc1[jj];
    r[16] = l1;
    if (p2 < PP) {
      float* r2 = smem_f + ((size_t)w * PP + p2) * 17;
#pragma unroll
      for (int jj = 0; jj < QDQ; ++jj) r2[jj] = acc2[jj];
      r2[16] = l2;
    }
  }
  __syncthreads();
  if (w >= 4) {
    float* r = smem_f + ((size_t)(w - 4) * PP + lane) * 17;
#pragma unroll
    for (int jj = 0; jj < QDQ; ++jj) r[jj] += acc1[jj];
    r[16] += l1;
    if (p2 < PP) {
      float* r2 = smem_f + ((size_t)(w - 4) * PP + p2) * 17;
#pragma unroll
      for (int jj = 0; jj < QDQ; ++jj) r2[jj] += acc2[jj];
      r2[16] += l2;
    }
  }
  __syncthreads();
  for (int idx = tid; idx < PP * 17; idx += 512) {
    int pp2 = idx / 17, e = idx % 17;
    float vsum = smem_f[(0 * PP + pp2) * 17 + e] + smem_f[(1 * PP + pp2) * 17 + e]
               + smem_f[(2 * PP + pp2) * 17 + e] + smem_f[(3 * PP + pp2) * 17 + e];
    part[((size_t)swz * PP + pp2) * 17 + e] = vsum;
  }
}

// ---------------- Kernel C: merge 2 halves (sum) + mh_combine (LDS GEMM) ------
__global__ __launch_bounds__(256) void k_combine(const float* __restrict__ part,
                                                 const float* __restrict__ MC,
                                                 float* __restrict__ mh) {
  __shared__ float sw[128 * 65];       // MC[j][dl] current half, padded
  __shared__ float oc[QROWS * DD];
  int tid = threadIdx.x;
  int row0 = blockIdx.x * QROWS;

  for (int i = tid; i < QROWS * DD; i += 256) {
    int r = i >> 7, t = i & 127;
    int bp = row0 + r, b = bp / PP, p = bp % PP;
    int qd = t & 15, h = t >> 4;
    int bh = b * HH + h;
    const float* r0 = part + (((size_t)(bh * 2 + 0)) * PP + p) * 17;
    const float* r1 = part + (((size_t)(bh * 2 + 1)) * PP + p) * 17;
    float A = r0[qd] + r1[qd];
    float L = r0[16] + r1[16];
    oc[i] = A / L;
  }

  int j = tid & 127, rr = tid >> 7;
  float acc[8];
#pragma unroll
  for (int i = 0; i < 8; ++i) acc[i] = 0.f;

  for (int half = 0; half < 2; ++half) {
    __syncthreads();
    for (int idx = tid; idx < 128 * 64; idx += 256) {
      int jj = idx >> 6, dl = idx & 63;
      sw[jj * 65 + dl] = MC[jj * DD + half * 64 + dl];
    }
    __syncthreads();
#pragma unroll
    for (int ri = 0; ri < 8; ++ri) {
      int r = 2 * ri + rr;
      float a = acc[ri];
#pragma unroll 16
      for (int dl = 0; dl < 64; ++dl)
        a += oc[r * DD + half * 64 + dl] * sw[j * 65 + dl];
      acc[ri] = a;
    }
  }
#pragma unroll
  for (int ri = 0; ri < 8; ++ri) {
    int bp = row0 + 2 * ri + rr;
    mh[(size_t)bp * DD + j] = acc[ri];
  }
}

// ------- Kernel D: score2 (packed f32: two n-columns per accumulator) --------
__global__ __launch_bounds__(256) void k_score2(const float* __restrict__ mh,
                                                const float* __restrict__ shk,
                                                float* __restrict__ sc) {
  int bid = blockIdx.x;
  int swz = (bid & 7) * 128 + (bid >> 3);      // same-b blocks share an XCD
  int b = swz >> 4, nt = swz & 15;
  int tid = threadIdx.x; int nl = tid & 31, pg = tid >> 5;
  __shared__ float A[PP * 132];
  for (int idx = tid; idx < PP * DD; idx += 256)
    A[(idx >> 7) * 132 + (idx & 127)] = mh[(size_t)b * PP * DD + idx];
  __syncthreads();

  int na = nt * 64 + nl, nb2 = na + 32;
  int nca = na < NN ? na : NN - 1, ncb = nb2 < NN ? nb2 : NN - 1;
  const float* S = shk + (size_t)b * DD * NN;
  f2 accv[13];
#pragma unroll
  for (int i = 0; i < 13; ++i) accv[i] = splat2(0.f);

  for (int d = 0; d < DD; d += 4) {
    f2 s0, s1, s2, s3;
    s0.x = S[(size_t)(d + 0) * NN + nca]; s0.y = S[(size_t)(d + 0) * NN + ncb];
    s1.x = S[(size_t)(d + 1) * NN + nca]; s1.y = S[(size_t)(d + 1) * NN + ncb];
    s2.x = S[(size_t)(d + 2) * NN + nca]; s2.y = S[(size_t)(d + 2) * NN + ncb];
    s3.x = S[(size_t)(d + 3) * NN + nca]; s3.y = S[(size_t)(d + 3) * NN + ncb];
#pragma unroll
    for (int i = 0; i < 13; ++i) {
      int p = pg + (i << 3);
      if (p < PP) {
        const float4 a4 = *(const float4*)&A[p * 132 + d];
        accv[i] = PKFMA(splat2(a4.x), s0, accv[i]);
        accv[i] = PKFMA(splat2(a4.y), s1, accv[i]);
        accv[i] = PKFMA(splat2(a4.z), s2, accv[i]);
        accv[i] = PKFMA(splat2(a4.w), s3, accv[i]);
      }
    }
  }
#pragma unroll
  for (int i = 0; i < 13; ++i) {
    int p = pg + (i << 3);
    if (p < PP) {
      size_t base = ((size_t)b * PP + p) * NN;
      if (na < NN) sc[base + na] = accv[i].x;
      if (nb2 < NN) sc[base + nb2] = accv[i].y;
    }
  }
}

// ------- Kernel E: tanh clip + edge bias + mask + row softmax (no max pass) ---
// Logits bounded (|10 tanh| <= 10, bias small), so exp2 without max-subtraction
// is safe; masked -inf still -> 0 and no (-inf)-(-inf) NaN can occur.
__global__ __launch_bounds__(256) void k_finsm(const float* __restrict__ sc,
                                               const float* __restrict__ eb,
                                               const int* __restrict__ cn,
                                               const float* __restrict__ mask,
                                               float* __restrict__ out) {
  int bid = blockIdx.x;
  int bp = (bid & 7) * 800 + (bid >> 3);       // XCD swizzle (6400 % 8 == 0)
  int b = bp / PP;
  int t = threadIdx.x;
  int node = cn[bp];
  const float* scp = sc + (size_t)bp * NN;
  const float* ebp = eb + ((size_t)b * NN + node) * NN;
  const float* mp = mask + (size_t)bp * NN;
  const float inv_sqrtD = 0.08838834764831845f;  // 1/sqrt(128)

  float vals[4];
  float s = 0.f;
#pragma unroll
  for (int i = 0; i < 4; ++i) {
    int n = t + (i << 8);
    if (n < NN) {
      float z = scp[n] * inv_sqrtD;
      float e = EXP2(2.f * LOG2E * z);
      float th10 = 10.f - 20.f * __builtin_amdgcn_rcpf(e + 1.f);  // 10*tanh(z)
      float lg = th10 + ebp[n] + mp[n];
      float e2 = EXP2(lg * LOG2E);
      vals[i] = e2;
      s += e2;
    } else {
      vals[i] = 0.f;
    }
  }
#pragma unroll
  for (int off = 32; off; off >>= 1) s += __shfl_xor(s, off);
  __shared__ float red[4];
  int w = t >> 6, lane = t & 63;
  if (lane == 0) red[w] = s;
  __syncthreads();
  s = (red[0] + red[1]) + (red[2] + red[3]);
  float inv = 1.f / s;
#pragma unroll
  for (int i = 0; i < 4; ++i) {
    int n = t + (i << 8);
    if (n < NN) out[(size_t)bp * NN + n] = vals[i] * inv;
  }
}

extern "C" void kernel_launch(void* const* d_in, const int* in_sizes, int n_in,
                              void* d_out, int out_size, void* d_ws, size_t ws_size,
                              hipStream_t stream) {
  const float* x    = (const float*)d_in[0];   // encoded_last_node (B,P,D)
  const float* mask = (const float*)d_in[1];   // ninf_mask (B,P,N)
  const float* qf   = (const float*)d_in[2];   // q_first (B,H,P,QD)
  const float* kk   = (const float*)d_in[3];   // k (B,H,NTOT,QD)
  const float* vv   = (const float*)d_in[4];   // v (B,H,NTOT,QD)
  const float* shk  = (const float*)d_in[5];   // single_head_key (B,D,N)
  const float* Wq   = (const float*)d_in[6];   // (128,128)
  const float* MC   = (const float*)d_in[7];   // (128,128)
  const float* eb   = (const float*)d_in[8];   // edge_bias (B,N,N)
  const int*   cn   = (const int*)d_in[9];     // current_node (B,P)

  float* out = (float*)d_out;
  float* ws = (float*)d_ws;
  float* q_ws = ws;                            //   819,200 f
  float* part = ws + 819200;                   // 1,740,800 f (1024*100*17)
  float* mh   = ws + 2560000;                  //   819,200 f
  float* reg  = ws + 3379200;                  // 6,400,000 f shared region:
  __hip_bfloat16* mt = (__hip_bfloat16*)reg;   //   mt bf16 (9,797,632 ush = 4.9M f)
  float* sc   = reg;                           //   sc overlays mt (after last mt read)

  hipLaunchKernelGGL(k_prep, dim3(2832), dim3(256), 0, stream, x, Wq, qf, q_ws, mask, mt);
  hipLaunchKernelGGL(k_mha, dim3(1024), dim3(512), 0, stream, kk, vv, q_ws,
                     (const unsigned int*)mt, part);
  hipLaunchKernelGGL(k_combine, dim3(400), dim3(256), 0, stream, part, MC, mh);
  hipLaunchKernelGGL(k_score2, dim3(1024), dim3(256), 0, stream, mh, shk, sc);
  hipLaunchKernelGGL(k_finsm, dim3(6400), dim3(256), 0, stream, sc, eb, cn, mask, out);
}

// Round 13
// 199.968 us; speedup vs baseline: 1.3471x; 1.0998x over previous
//
#include <hip/hip_runtime.h>
#include <math.h>

#define BB 64
#define PP 100
#define NN 1000
#define DD 128
#define HH 8
#define QDQ 16
#define NTOT 1196
#define QROWS 16
#define LOG2E 1.44269504088896f
#define EXP2(x) __builtin_amdgcn_exp2f(x)

typedef float f2 __attribute__((ext_vector_type(2)));
typedef short s8v __attribute__((ext_vector_type(8)));
typedef float f16v __attribute__((ext_vector_type(16)));

static __device__ __forceinline__ f2 splat2(float v) { f2 r; r.x = v; r.y = v; return r; }
#define PKFMA(a, b, c) __builtin_elementwise_fma((a), (b), (c))

static __device__ __forceinline__ unsigned pkhi(float a, float b) {
  return (__float_as_uint(a) >> 16) | (__float_as_uint(b) & 0xffff0000u);
}
static __device__ __forceinline__ float truncbf(float a) {
  return __uint_as_float(__float_as_uint(a) & 0xffff0000u);
}
#define MFMA32(a, b, c) __builtin_amdgcn_mfma_f32_32x32x16_bf16((a), (b), (c), 0, 0, 0)

// ------- Kernel P: fused {q = q_first + x @ Wq^T} and {mask2 bf16 table} ------
// blocks 0..399: qcalc (16 bp-rows each); blocks 400..8591: mask2 rows (b,q).
// mask2[b][q][j]: j = h*640 + jj; jj<598 -> key n = h*598+jj: n<1000: mask*log2e-20,
// 1000<=n<1196 (patch): -20; jj>=598 or q>=100: -1e4 (dead).
__global__ __launch_bounds__(256) void k_prep(const float* __restrict__ x,
                                              const float* __restrict__ Wq,
                                              const float* __restrict__ qf,
                                              float* __restrict__ qout,
                                              const float* __restrict__ mask,
                                              unsigned short* __restrict__ m2) {
  __shared__ float sw[128 * 65];
  __shared__ float xs[QROWS * DD];
  int tid = threadIdx.x;

  if (blockIdx.x < 400) {
    int row0 = blockIdx.x * QROWS;
    for (int i = tid; i < QROWS * DD / 4; i += 256)
      ((float4*)xs)[i] = ((const float4*)(x + (size_t)row0 * DD))[i];

    int j = tid & 127, rr = tid >> 7;
    float acc[8];
#pragma unroll
    for (int i = 0; i < 8; ++i) acc[i] = 0.f;

    for (int half = 0; half < 2; ++half) {
      __syncthreads();
      for (int idx = tid; idx < 128 * 64; idx += 256) {
        int jj = idx >> 6, dl = idx & 63;
        sw[jj * 65 + dl] = Wq[jj * DD + half * 64 + dl];
      }
      __syncthreads();
#pragma unroll
      for (int ri = 0; ri < 8; ++ri) {
        int r = 2 * ri + rr;
        float a = acc[ri];
#pragma unroll 16
        for (int dl = 0; dl < 64; ++dl)
          a += xs[r * DD + half * 64 + dl] * sw[j * 65 + dl];
        acc[ri] = a;
      }
    }
#pragma unroll
    for (int ri = 0; ri < 8; ++ri) {
      int bp = row0 + 2 * ri + rr;
      int b = bp / PP, p = bp % PP;
      int h = j >> 4, qd = j & 15;
      size_t qi = ((size_t)(b * HH + h) * PP + p) * QDQ + qd;
      qout[qi] = acc[ri] + qf[qi];
    }
  } else {
    int t2 = blockIdx.x - 400;
    int b = t2 >> 7, q = t2 & 127;
    unsigned short* dst = m2 + (size_t)(b * 128 + q) * 1280;
    const float* srow = mask + ((size_t)b * PP + (q < PP ? q : PP - 1)) * NN;
    for (int j = tid; j < 1280; j += 256) {
      int h = j >= 640 ? 1 : 0;
      int jj = j - h * 640;
      float val;
      if (q >= PP || jj >= 598) {
        val = -1e4f;
      } else {
        int n = h * 598 + jj;
        val = (n < NN) ? srow[n] * LOG2E - 20.f : -20.f;
      }
      dst[j] = (unsigned short)(__float_as_uint(val) >> 16);
    }
  }
}

// ---------------- Kernel B: MFMA MHA partial (split-bf16, swapped QK^T) -------
// grid = 1024 (XCD-swizzled: 512 bh * 2 halves); block = 256 (4 waves).
// Per chunk of 128 keys: stage K rows [key][Kh16|Kl16] bf16 and V^T [qd][key]
// hi/lo bf16 in LDS; wave w computes 32-key tile w. Per (key-tile, q-tile):
// S^T = mfma(K, Q^T) with C init = mask (-20, log2e folded); exp2 lane-local;
// P -> bf16 hi/lo A-frags via shfl_xor(32) half-exchange; O += mfma(P, V).
__global__ __launch_bounds__(256) void k_mha(const float* __restrict__ kk,
                                             const float* __restrict__ vv,
                                             const float* __restrict__ qws,
                                             const unsigned short* __restrict__ m2,
                                             float* __restrict__ part) {
  int bid = blockIdx.x;
  int swz = (bid & 7) * 128 + (bid >> 3);
  int bh = swz >> 1, half = swz & 1;
  int b = bh >> 3;
  int tid = threadIdx.x;
  int w = tid >> 6, lane = tid & 63;
  int L = lane >> 5, ln = lane & 31;
  bool lo = (L == 0);

  __shared__ __align__(16) char pool[27264];
  char* KspB = pool;                 // ushort [128][32] : [Kh(16)|Kl(16)] per key
  char* VThB = pool + 8192;          // ushort [16][128] : V^T hi
  char* VTlB = pool + 12288;         // ushort [16][128] : V^T lo
  char* QhB  = pool + 16384;         // ushort [128][16]
  char* QlB  = pool + 20480;

  // ---- stage Q (scaled, split) ----
  {
    const float* qrow = qws + (size_t)bh * (PP * QDQ);
    for (int i = tid; i < 128 * 16; i += 256) {
      int p = i >> 4, qd = i & 15;
      float v = (p < PP) ? qrow[p * QDQ + qd] * (0.25f * LOG2E) : 0.f;
      ((unsigned short*)QhB)[i] = (unsigned short)(__float_as_uint(v) >> 16);
      float rl = v - truncbf(v);
      ((unsigned short*)QlB)[i] = (unsigned short)(__float_as_uint(rl) >> 16);
    }
  }

  const float4* kf4 = (const float4*)kk + (size_t)bh * NTOT * 4;
  const float4* vf4 = (const float4*)vv + (size_t)bh * NTOT * 4;

  f16v Oacc[4];
  float lacc[4];
#pragma unroll
  for (int qt = 0; qt < 4; ++qt) {
    lacc[qt] = 0.f;
#pragma unroll
    for (int r = 0; r < 16; ++r) Oacc[qt][r] = 0.f;
  }
  s8v QhF[4], QlF[4];

  for (int c = 0; c < 5; ++c) {
    __syncthreads();
    // ---- stage 128 keys ----
#pragma unroll
    for (int rep = 0; rep < 2; ++rep) {
      int f = tid + rep * 256;
      int key_l = f >> 2, qd0 = (f & 3) << 2;
      int j = c * 128 + key_l;
      int jc = j < 598 ? j : 597;
      size_t gidx = (size_t)(half * 598 + jc) * 4 + (qd0 >> 2);
      float4 k4 = kf4[gidx];
      unsigned kh01 = pkhi(k4.x, k4.y), kh23 = pkhi(k4.z, k4.w);
      float r0 = k4.x - truncbf(k4.x), r1 = k4.y - truncbf(k4.y);
      float r2 = k4.z - truncbf(k4.z), r3 = k4.w - truncbf(k4.w);
      unsigned kl01 = pkhi(r0, r1), kl23 = pkhi(r2, r3);
      *(uint2*)(KspB + key_l * 64 + qd0 * 2) = make_uint2(kh01, kh23);
      *(uint2*)(KspB + key_l * 64 + 32 + qd0 * 2) = make_uint2(kl01, kl23);
      float4 v4 = vf4[gidx];
      float ve0 = v4.x, ve1 = v4.y, ve2 = v4.z, ve3 = v4.w;
      ((unsigned short*)VThB)[(qd0 + 0) * 128 + key_l] = (unsigned short)(__float_as_uint(ve0) >> 16);
      ((unsigned short*)VThB)[(qd0 + 1) * 128 + key_l] = (unsigned short)(__float_as_uint(ve1) >> 16);
      ((unsigned short*)VThB)[(qd0 + 2) * 128 + key_l] = (unsigned short)(__float_as_uint(ve2) >> 16);
      ((unsigned short*)VThB)[(qd0 + 3) * 128 + key_l] = (unsigned short)(__float_as_uint(ve3) >> 16);
      float w0 = ve0 - truncbf(ve0), w1 = ve1 - truncbf(ve1);
      float w2 = ve2 - truncbf(ve2), w3 = ve3 - truncbf(ve3);
      ((unsigned short*)VTlB)[(qd0 + 0) * 128 + key_l] = (unsigned short)(__float_as_uint(w0) >> 16);
      ((unsigned short*)VTlB)[(qd0 + 1) * 128 + key_l] = (unsigned short)(__float_as_uint(w1) >> 16);
      ((unsigned short*)VTlB)[(qd0 + 2) * 128 + key_l] = (unsigned short)(__float_as_uint(w2) >> 16);
      ((unsigned short*)VTlB)[(qd0 + 3) * 128 + key_l] = (unsigned short)(__float_as_uint(w3) >> 16);
    }
    __syncthreads();
    if (c == 0) {
#pragma unroll
      for (int qt = 0; qt < 4; ++qt) {
        int qr = qt * 32 + ln;
        QhF[qt] = *(const s8v*)(QhB + qr * 32 + L * 16);
        QlF[qt] = *(const s8v*)(QlB + qr * 32 + L * 16);
      }
    }
    // ---- compute this wave's 32-key tile ----
    int ktb = w * 32;
    s8v KhF = *(const s8v*)(KspB + (ktb + ln) * 64 + L * 16);
    s8v KlF = *(const s8v*)(KspB + (ktb + ln) * 64 + 32 + L * 16);
    int vr = ln & 15;
    s8v VhS0 = *(const s8v*)(VThB + vr * 256 + (ktb + L * 8) * 2);
    s8v VhS1 = *(const s8v*)(VThB + vr * 256 + (ktb + 16 + L * 8) * 2);
    s8v VlS0 = *(const s8v*)(VTlB + vr * 256 + (ktb + L * 8) * 2);
    s8v VlS1 = *(const s8v*)(VTlB + vr * 256 + (ktb + 16 + L * 8) * 2);
    size_t mkey = (size_t)half * 640 + c * 128 + ktb + 4 * L;
#pragma unroll
    for (int qt = 0; qt < 4; ++qt) {
      const unsigned short* mrow = m2 + (size_t)(b * 128 + qt * 32 + ln) * 1280 + mkey;
      f16v acc;
#pragma unroll
      for (int g = 0; g < 4; ++g) {
        uint2 md = *(const uint2*)(mrow + g * 8);
        acc[g * 4 + 0] = __uint_as_float(md.x << 16);
        acc[g * 4 + 1] = __uint_as_float(md.x & 0xffff0000u);
        acc[g * 4 + 2] = __uint_as_float(md.y << 16);
        acc[g * 4 + 3] = __uint_as_float(md.y & 0xffff0000u);
      }
      acc = MFMA32(KhF, QhF[qt], acc);
      acc = MFMA32(KhF, QlF[qt], acc);
      acc = MFMA32(KlF, QhF[qt], acc);
      float p[16];
      float ls = 0.f;
#pragma unroll
      for (int r = 0; r < 16; ++r) { p[r] = EXP2(acc[r]); ls += p[r]; }
      lacc[qt] += ls;
#pragma unroll
      for (int s = 0; s < 2; ++s) {
        unsigned a0 = pkhi(p[8 * s + 0], p[8 * s + 1]), a1 = pkhi(p[8 * s + 2], p[8 * s + 3]);
        unsigned b0 = pkhi(p[8 * s + 4], p[8 * s + 5]), b1 = pkhi(p[8 * s + 6], p[8 * s + 7]);
        unsigned sa0 = __shfl_xor(a0, 32), sa1 = __shfl_xor(a1, 32);
        unsigned sb0 = __shfl_xor(b0, 32), sb1 = __shfl_xor(b1, 32);
        uint4 phu = make_uint4(lo ? a0 : sb0, lo ? a1 : sb1, lo ? sa0 : b0, lo ? sa1 : b1);
        float t0 = p[8 * s + 0] - truncbf(p[8 * s + 0]), t1 = p[8 * s + 1] - truncbf(p[8 * s + 1]);
        float t2 = p[8 * s + 2] - truncbf(p[8 * s + 2]), t3 = p[8 * s + 3] - truncbf(p[8 * s + 3]);
        float t4 = p[8 * s + 4] - truncbf(p[8 * s + 4]), t5 = p[8 * s + 5] - truncbf(p[8 * s + 5]);
        float t6 = p[8 * s + 6] - truncbf(p[8 * s + 6]), t7 = p[8 * s + 7] - truncbf(p[8 * s + 7]);
        unsigned c0 = pkhi(t0, t1), c1 = pkhi(t2, t3);
        unsigned e0 = pkhi(t4, t5), e1 = pkhi(t6, t7);
        unsigned sc0 = __shfl_xor(c0, 32), sc1 = __shfl_xor(c1, 32);
        unsigned se0 = __shfl_xor(e0, 32), se1 = __shfl_xor(e1, 32);
        uint4 plu = make_uint4(lo ? c0 : se0, lo ? c1 : se1, lo ? sc0 : e0, lo ? sc1 : e1);
        s8v APh = *(s8v*)&phu;
        s8v APl = *(s8v*)&plu;
        s8v Vh = s ? VhS1 : VhS0;
        s8v Vl = s ? VlS1 : VlS0;
        Oacc[qt] = MFMA32(APh, Vh, Oacc[qt]);
        Oacc[qt] = MFMA32(APh, Vl, Oacc[qt]);
        Oacc[qt] = MFMA32(APl, Vh, Oacc[qt]);
      }
    }
  }

  // ---- merge 4 waves -> part records [q][17] (unnormalized A + l) ----
  float lf[4];
#pragma unroll
  for (int qt = 0; qt < 4; ++qt) lf[qt] = lacc[qt] + __shfl_xor(lacc[qt], 32);

  __syncthreads();
  float* marea = (float*)pool;                 // [4][100][16]
  float* larea = (float*)(pool + 25600);       // [4][100]
  if (ln < 16) {
#pragma unroll
    for (int qt = 0; qt < 4; ++qt) {
#pragma unroll
      for (int r = 0; r < 16; ++r) {
        int q = qt * 32 + (r & 3) + 8 * (r >> 2) + 4 * L;
        if (q < PP) marea[(w * PP + q) * 16 + ln] = Oacc[qt][r];
      }
    }
  }
  if (lane < 32) {
#pragma unroll
    for (int qt = 0; qt < 4; ++qt) {
      int q = qt * 32 + ln;
      if (q < PP) larea[w * PP + q] = lf[qt];
    }
  }
  __syncthreads();
  for (int idx = tid; idx < PP * 17; idx += 256) {
    int q = idx / 17, e = idx % 17;
    float sv;
    if (e < 16)
      sv = marea[(0 * PP + q) * 16 + e] + marea[(1 * PP + q) * 16 + e]
         + marea[(2 * PP + q) * 16 + e] + marea[(3 * PP + q) * 16 + e];
    else
      sv = larea[0 * PP + q] + larea[1 * PP + q] + larea[2 * PP + q] + larea[3 * PP + q];
    part[((size_t)swz * PP + q) * 17 + e] = sv;
  }
}

// ---------------- Kernel C: merge 2 halves (sum) + mh_combine (LDS GEMM) ------
__global__ __launch_bounds__(256) void k_combine(const float* __restrict__ part,
                                                 const float* __restrict__ MC,
                                                 float* __restrict__ mh) {
  __shared__ float sw[128 * 65];
  __shared__ float oc[QROWS * DD];
  int tid = threadIdx.x;
  int row0 = blockIdx.x * QROWS;

  for (int i = tid; i < QROWS * DD; i += 256) {
    int r = i >> 7, t = i & 127;
    int bp = row0 + r, b = bp / PP, p = bp % PP;
    int qd = t & 15, h = t >> 4;
    int bh = b * HH + h;
    const float* r0 = part + (((size_t)(bh * 2 + 0)) * PP + p) * 17;
    const float* r1 = part + (((size_t)(bh * 2 + 1)) * PP + p) * 17;
    float A = r0[qd] + r1[qd];
    float L = r0[16] + r1[16];
    oc[i] = A / L;
  }

  int j = tid & 127, rr = tid >> 7;
  float acc[8];
#pragma unroll
  for (int i = 0; i < 8; ++i) acc[i] = 0.f;

  for (int half = 0; half < 2; ++half) {
    __syncthreads();
    for (int idx = tid; idx < 128 * 64; idx += 256) {
      int jj = idx >> 6, dl = idx & 63;
      sw[jj * 65 + dl] = MC[jj * DD + half * 64 + dl];
    }
    __syncthreads();
#pragma unroll
    for (int ri = 0; ri < 8; ++ri) {
      int r = 2 * ri + rr;
      float a = acc[ri];
#pragma unroll 16
      for (int dl = 0; dl < 64; ++dl)
        a += oc[r * DD + half * 64 + dl] * sw[j * 65 + dl];
      acc[ri] = a;
    }
  }
#pragma unroll
  for (int ri = 0; ri < 8; ++ri) {
    int bp = row0 + 2 * ri + rr;
    mh[(size_t)bp * DD + j] = acc[ri];
  }
}

// ------- Kernel D: score2 (packed f32: two n-columns per accumulator) --------
__global__ __launch_bounds__(256) void k_score2(const float* __restrict__ mh,
                                                const float* __restrict__ shk,
                                                float* __restrict__ sc) {
  int bid = blockIdx.x;
  int swz = (bid & 7) * 128 + (bid >> 3);
  int b = swz >> 4, nt = swz & 15;
  int tid = threadIdx.x; int nl = tid & 31, pg = tid >> 5;
  __shared__ float A[PP * 132];
  for (int idx = tid; idx < PP * DD; idx += 256)
    A[(idx >> 7) * 132 + (idx & 127)] = mh[(size_t)b * PP * DD + idx];
  __syncthreads();

  int na = nt * 64 + nl, nb2 = na + 32;
  int nca = na < NN ? na : NN - 1, ncb = nb2 < NN ? nb2 : NN - 1;
  const float* S = shk + (size_t)b * DD * NN;
  f2 accv[13];
#pragma unroll
  for (int i = 0; i < 13; ++i) accv[i] = splat2(0.f);

  for (int d = 0; d < DD; d += 4) {
    f2 s0, s1, s2, s3;
    s0.x = S[(size_t)(d + 0) * NN + nca]; s0.y = S[(size_t)(d + 0) * NN + ncb];
    s1.x = S[(size_t)(d + 1) * NN + nca]; s1.y = S[(size_t)(d + 1) * NN + ncb];
    s2.x = S[(size_t)(d + 2) * NN + nca]; s2.y = S[(size_t)(d + 2) * NN + ncb];
    s3.x = S[(size_t)(d + 3) * NN + nca]; s3.y = S[(size_t)(d + 3) * NN + ncb];
#pragma unroll
    for (int i = 0; i < 13; ++i) {
      int p = pg + (i << 3);
      if (p < PP) {
        const float4 a4 = *(const float4*)&A[p * 132 + d];
        accv[i] = PKFMA(splat2(a4.x), s0, accv[i]);
        accv[i] = PKFMA(splat2(a4.y), s1, accv[i]);
        accv[i] = PKFMA(splat2(a4.z), s2, accv[i]);
        accv[i] = PKFMA(splat2(a4.w), s3, accv[i]);
      }
    }
  }
#pragma unroll
  for (int i = 0; i < 13; ++i) {
    int p = pg + (i << 3);
    if (p < PP) {
      size_t base = ((size_t)b * PP + p) * NN;
      if (na < NN) sc[base + na] = accv[i].x;
      if (nb2 < NN) sc[base + nb2] = accv[i].y;
    }
  }
}

// ------- Kernel E: tanh clip + edge bias + mask + row softmax (no max pass) ---
__global__ __launch_bounds__(256) void k_finsm(const float* __restrict__ sc,
                                               const float* __restrict__ eb,
                                               const int* __restrict__ cn,
                                               const float* __restrict__ mask,
                                               float* __restrict__ out) {
  int bid = blockIdx.x;
  int bp = (bid & 7) * 800 + (bid >> 3);
  int b = bp / PP;
  int t = threadIdx.x;
  int node = cn[bp];
  const float* scp = sc + (size_t)bp * NN;
  const float* ebp = eb + ((size_t)b * NN + node) * NN;
  const float* mp = mask + (size_t)bp * NN;
  const float inv_sqrtD = 0.08838834764831845f;

  float vals[4];
  float s = 0.f;
#pragma unroll
  for (int i = 0; i < 4; ++i) {
    int n = t + (i << 8);
    if (n < NN) {
      float z = scp[n] * inv_sqrtD;
      float e = EXP2(2.f * LOG2E * z);
      float th10 = 10.f - 20.f * __builtin_amdgcn_rcpf(e + 1.f);
      float lg = th10 + ebp[n] + mp[n];
      float e2 = EXP2(lg * LOG2E);
      vals[i] = e2;
      s += e2;
    } else {
      vals[i] = 0.f;
    }
  }
#pragma unroll
  for (int off = 32; off; off >>= 1) s += __shfl_xor(s, off);
  __shared__ float red[4];
  int w = t >> 6, lane = t & 63;
  if (lane == 0) red[w] = s;
  __syncthreads();
  s = (red[0] + red[1]) + (red[2] + red[3]);
  float inv = 1.f / s;
#pragma unroll
  for (int i = 0; i < 4; ++i) {
    int n = t + (i << 8);
    if (n < NN) out[(size_t)bp * NN + n] = vals[i] * inv;
  }
}

extern "C" void kernel_launch(void* const* d_in, const int* in_sizes, int n_in,
                              void* d_out, int out_size, void* d_ws, size_t ws_size,
                              hipStream_t stream) {
  const float* x    = (const float*)d_in[0];   // encoded_last_node (B,P,D)
  const float* mask = (const float*)d_in[1];   // ninf_mask (B,P,N)
  const float* qf   = (const float*)d_in[2];   // q_first (B,H,P,QD)
  const float* kk   = (const float*)d_in[3];   // k (B,H,NTOT,QD)
  const float* vv   = (const float*)d_in[4];   // v (B,H,NTOT,QD)
  const float* shk  = (const float*)d_in[5];   // single_head_key (B,D,N)
  const float* Wq   = (const float*)d_in[6];   // (128,128)
  const float* MC   = (const float*)d_in[7];   // (128,128)
  const float* eb   = (const float*)d_in[8];   // edge_bias (B,N,N)
  const int*   cn   = (const int*)d_in[9];     // current_node (B,P)

  float* out = (float*)d_out;
  float* ws = (float*)d_ws;
  float* q_ws = ws;                            //   819,200 f
  float* part = ws + 819200;                   // 1,740,800 f (1024*100*17)
  float* mh   = ws + 2560000;                  //   819,200 f
  float* reg  = ws + 3379200;                  // 6,400,000 f shared region:
  unsigned short* m2 = (unsigned short*)reg;   //   mask2 (64*128*1280 ush = 5.24M f)
  float* sc   = reg;                           //   sc overlays m2 (after last m2 read)

  hipLaunchKernelGGL(k_prep, dim3(8592), dim3(256), 0, stream, x, Wq, qf, q_ws, mask, m2);
  hipLaunchKernelGGL(k_mha, dim3(1024), dim3(256), 0, stream, kk, vv, q_ws, m2, part);
  hipLaunchKernelGGL(k_combine, dim3(400), dim3(256), 0, stream, part, MC, mh);
  hipLaunchKernelGGL(k_score2, dim3(1024), dim3(256), 0, stream, mh, shk, sc);
  hipLaunchKernelGGL(k_finsm, dim3(6400), dim3(256), 0, stream, sc, eb, cn, mask, out);
}